// Round 5
// baseline (2437.717 us; speedup 1.0000x reference)
//
#include <hip/hip_runtime.h>
#include <math.h>

// ---------------------------------------------------------------------------
// Com_CNN_RNN: 2-epoch stacked GRU (T=256, E=512) -> conv1d+maxpool (degenerate
// global max) -> GRU2 (T=2) -> similarity head. Full fp32.
//
// R4: data-as-flag sync. GRU h satisfies |h|<1 strictly, so 2.0f is an
// impossible value -> poison. hstep[t>=1] pre-poisoned; producers fire relaxed
// sc1 stores (no drain, no flag, no fence); wave 0 of each WG polls the data
// words directly and stages into double-buffered LDS; ONE barrier per step.
// 32 WGs x 512 thr per chain, 48 weight floats/thread register-resident.
// ---------------------------------------------------------------------------

__device__ __forceinline__ float sigm(float x) { return 1.f / (1.f + expf(-x)); }

#define POISON_U32 0x40000000u   // 2.0f — unreachable for GRU h (|h|<1)

// LDS index map: p(k) = k + (k>>4)*4 (pad 4 words per 16; keeps float4 align)
#define LDSP(k) ((k) + (((k) >> 4) << 2))

// mode 0: gi precomputed in global [2][T][1536]   (T=256)
// mode 1: gi from xin [2][2][512] with Wih/bih in prologue (T=2)
// mode 2: gi = mscal[s*2+t] * Srow[row] + bih[row] (T=2)
__global__ __launch_bounds__(512, 2) void k_chain5(
    const float* __restrict__ Whh, const float* __restrict__ bhh,
    const float* __restrict__ gi,
    const float* __restrict__ Wih, const float* __restrict__ bih,
    const float* __restrict__ xin,
    const float* __restrict__ mscal, const float* __restrict__ Srow,
    float* __restrict__ xout,            // [2][T][512] or null
    float* __restrict__ finout, long fin_ss,
    float* __restrict__ hstep,           // [T+1][2][512], t=0 zeroed, rest poison
    int T, int mode)
{
    const int tid  = threadIdx.x;
    const int wgi  = blockIdx.x;         // 0..31
    const int grp  = tid >> 5;           // 0..15
    const int lane = tid & 31;           // 32 lanes per row
    const int j    = wgi * 16 + grp;     // h row 0..511
    const int colbase = lane * 16;       // 16 k-columns per lane

    __shared__ float hlds[2][1280];      // double-buffered staged h

    // ---- register-resident weights: rows {j,512+j,1024+j} x 16 cols ----
    float wreg[3][16];
#pragma unroll
    for (int q = 0; q < 3; ++q) {
        const float* src = Whh + (size_t)(q * 512 + j) * 512 + colbase;
#pragma unroll
        for (int c4 = 0; c4 < 4; ++c4) {
            float4 v = *(const float4*)(src + c4 * 4);
            wreg[q][c4 * 4 + 0] = v.x; wreg[q][c4 * 4 + 1] = v.y;
            wreg[q][c4 * 4 + 2] = v.z; wreg[q][c4 * 4 + 3] = v.w;
        }
    }
#pragma unroll
    for (int q = 0; q < 3; ++q)
#pragma unroll
        for (int c = 0; c < 16; ++c)
            asm volatile("" : "+v"(wreg[q][c]));

    float bhh_q[3];
#pragma unroll
    for (int q = 0; q < 3; ++q) bhh_q[q] = bhh[q * 512 + j];
    float bih_q[3] = {0.f, 0.f, 0.f};
    if (mode != 0) {
#pragma unroll
        for (int q = 0; q < 3; ++q) bih_q[q] = bih[q * 512 + j];
    }

    // ---- prologue gi for the T==2 modes: gp0 = step0, gp1 = step1 ----
    float gp0[3][2], gp1[3][2];
    if (mode == 1) {
#pragma unroll
        for (int t = 0; t < 2; ++t) {
#pragma unroll
            for (int s = 0; s < 2; ++s) {
                float xr[16];
                const float* xp = xin + (size_t)s * 1024 + (size_t)t * 512 + colbase;
#pragma unroll
                for (int c4 = 0; c4 < 4; ++c4) {
                    float4 v = *(const float4*)(xp + c4 * 4);
                    xr[c4*4+0] = v.x; xr[c4*4+1] = v.y;
                    xr[c4*4+2] = v.z; xr[c4*4+3] = v.w;
                }
#pragma unroll
                for (int q = 0; q < 3; ++q) {
                    const float* wp = Wih + (size_t)(q * 512 + j) * 512 + colbase;
                    float a = 0.f;
#pragma unroll
                    for (int c4 = 0; c4 < 4; ++c4) {
                        float4 w4 = *(const float4*)(wp + c4 * 4);
                        a += w4.x * xr[c4*4+0] + w4.y * xr[c4*4+1]
                           + w4.z * xr[c4*4+2] + w4.w * xr[c4*4+3];
                    }
#pragma unroll
                    for (int off = 16; off >= 1; off >>= 1)
                        a += __shfl_xor(a, off, 64);
                    a += bih_q[q];
                    if (t == 0) gp0[q][s] = a; else gp1[q][s] = a;
                }
            }
        }
    } else if (mode == 2) {
#pragma unroll
        for (int q = 0; q < 3; ++q) {
            float Sq = Srow[q * 512 + j];
#pragma unroll
            for (int s = 0; s < 2; ++s) {
                gp0[q][s] = mscal[s * 2 + 0] * Sq + bih_q[q];
                gp1[q][s] = mscal[s * 2 + 1] * Sq + bih_q[q];
            }
        }
    }

    float hprev[2] = {0.f, 0.f};         // own row's h_{t-1} (all lanes redundant)

    // ---- step loop ----
    for (int t = 0; t < T; ++t) {
        const int p = t & 1;

        // gi for this step (issued before the poll/barrier so latency hides)
        float g0[3][2];
        if (mode == 0) {
#pragma unroll
            for (int q = 0; q < 3; ++q)
#pragma unroll
                for (int s = 0; s < 2; ++s)
                    g0[q][s] = gi[(size_t)(s * T + t) * 1536 + q * 512 + j];
        } else {
#pragma unroll
            for (int q = 0; q < 3; ++q)
#pragma unroll
                for (int s = 0; s < 2; ++s)
                    g0[q][s] = (t == 0) ? gp0[q][s] : gp1[q][s];
        }

        // wave 0: poll h_t data directly (poison = not yet written), stage LDS
        if (tid < 64) {
            const unsigned long long* src =
                (const unsigned long long*)(hstep + (size_t)t * 1024 + tid * 16);
            union { unsigned long long u; float2 f; } v[8];
            bool ok = false;
            do {
#pragma unroll
                for (int i = 0; i < 8; ++i)
                    v[i].u = __hip_atomic_load(src + i, __ATOMIC_RELAXED,
                                               __HIP_MEMORY_SCOPE_AGENT);
                ok = true;
#pragma unroll
                for (int i = 0; i < 8; ++i) {
                    if ((unsigned)(v[i].u & 0xFFFFFFFFu) == POISON_U32) ok = false;
                    if ((unsigned)(v[i].u >> 32)         == POISON_U32) ok = false;
                }
            } while (!ok);
            float* dst = &hlds[p][LDSP(tid * 16)];
#pragma unroll
            for (int i = 0; i < 8; ++i) {
                dst[2 * i + 0] = v[i].f.x;
                dst[2 * i + 1] = v[i].f.y;
            }
        }
        __syncthreads();

        // gh partials: 3 gates x 2 sentences over this lane's 16 columns
        float accq[3][2];
#pragma unroll
        for (int q = 0; q < 3; ++q) { accq[q][0] = 0.f; accq[q][1] = 0.f; }
#pragma unroll
        for (int s = 0; s < 2; ++s) {
            const int base = s * 640 + 20 * lane;     // = LDSP(s*512+colbase)
#pragma unroll
            for (int c4 = 0; c4 < 4; ++c4) {
                float4 hv = *(const float4*)&hlds[p][base + c4 * 4];
#pragma unroll
                for (int q = 0; q < 3; ++q) {
                    accq[q][s] += wreg[q][c4*4+0] * hv.x + wreg[q][c4*4+1] * hv.y
                                + wreg[q][c4*4+2] * hv.z + wreg[q][c4*4+3] * hv.w;
                }
            }
        }
#pragma unroll
        for (int q = 0; q < 3; ++q)
#pragma unroll
            for (int s = 0; s < 2; ++s) {
                float v = accq[q][s];
                v += __shfl_xor(v, 16, 64);
                v += __shfl_xor(v, 8, 64);
                v += __shfl_xor(v, 4, 64);
                v += __shfl_xor(v, 2, 64);
                v += __shfl_xor(v, 1, 64);
                accq[q][s] = v;
            }

        float hn[2];
#pragma unroll
        for (int s = 0; s < 2; ++s) {
            const float rr = sigm(g0[0][s] + accq[0][s] + bhh_q[0]);
            const float zz = sigm(g0[1][s] + accq[1][s] + bhh_q[1]);
            const float nn = tanhf(g0[2][s] + rr * (accq[2][s] + bhh_q[2]));
            hn[s] = (1.f - zz) * nn + zz * hprev[s];
            hprev[s] = hn[s];
        }

        // publish: fire-and-forget relaxed sc1 stores (data IS the flag)
        if (lane == 0) {
#pragma unroll
            for (int s = 0; s < 2; ++s) {
                __hip_atomic_store(hstep + (size_t)(t + 1) * 1024 + s * 512 + j, hn[s],
                                   __ATOMIC_RELAXED, __HIP_MEMORY_SCOPE_AGENT);
                if (xout != nullptr)
                    xout[((size_t)s * T + t) * 512 + j] = hn[s];
                if (finout != nullptr && t == T - 1)
                    finout[(size_t)s * fin_ss + j] = hn[s];
            }
        }
        // no drain, no flag, no second barrier (LDS is double-buffered)
    }
}

// ---------------------------------------------------------------------------
// gi GEMM: out[m][n] = sum_k A[m][k] * W[n][k] + bias[n]; M=512, N=1536, K=512.
// ---------------------------------------------------------------------------
__global__ __launch_bounds__(256, 2) void k_gemm_gi(
    const float* __restrict__ W, const float* __restrict__ bias,
    const float* __restrict__ emb, const int* __restrict__ sentA,
    const int* __restrict__ sentB, const float* __restrict__ xsrc,
    float* __restrict__ out)
{
    __shared__ float At[32][68];
    __shared__ float Wt[32][68];
    const int tid = threadIdx.x;
    const int n0 = blockIdx.x * 64;
    const int m0 = blockIdx.y * 64;
    const int lrow = tid >> 3, lc4 = tid & 7;

    const float *ar0, *ar1;
    {
        const int ma = m0 + lrow, mb = ma + 32;
        if (emb != nullptr) {
            const int ia = (ma < 256) ? sentA[ma & 255] : sentB[ma & 255];
            const int ib = (mb < 256) ? sentA[mb & 255] : sentB[mb & 255];
            ar0 = emb + (size_t)ia * 512;
            ar1 = emb + (size_t)ib * 512;
        } else {
            ar0 = xsrc + (size_t)ma * 512;
            ar1 = xsrc + (size_t)mb * 512;
        }
    }
    const float* wr0 = W + (size_t)(n0 + lrow) * 512;
    const float* wr1 = wr0 + (size_t)32 * 512;

    const int ty = tid >> 4, tx = tid & 15;
    float acc[4][4];
#pragma unroll
    for (int i = 0; i < 4; ++i)
#pragma unroll
        for (int jj = 0; jj < 4; ++jj) acc[i][jj] = 0.f;

    for (int kk = 0; kk < 512; kk += 32) {
        float4 a0 = *(const float4*)(ar0 + kk + lc4 * 4);
        float4 a1 = *(const float4*)(ar1 + kk + lc4 * 4);
        float4 w0 = *(const float4*)(wr0 + kk + lc4 * 4);
        float4 w1 = *(const float4*)(wr1 + kk + lc4 * 4);
        __syncthreads();
        const int kb = lc4 * 4;
        At[kb+0][lrow] = a0.x; At[kb+1][lrow] = a0.y; At[kb+2][lrow] = a0.z; At[kb+3][lrow] = a0.w;
        At[kb+0][lrow+32] = a1.x; At[kb+1][lrow+32] = a1.y; At[kb+2][lrow+32] = a1.z; At[kb+3][lrow+32] = a1.w;
        Wt[kb+0][lrow] = w0.x; Wt[kb+1][lrow] = w0.y; Wt[kb+2][lrow] = w0.z; Wt[kb+3][lrow] = w0.w;
        Wt[kb+0][lrow+32] = w1.x; Wt[kb+1][lrow+32] = w1.y; Wt[kb+2][lrow+32] = w1.z; Wt[kb+3][lrow+32] = w1.w;
        __syncthreads();
#pragma unroll
        for (int k = 0; k < 32; ++k) {
            float4 av = *(const float4*)&At[k][ty * 4];
            float4 wv = *(const float4*)&Wt[k][tx * 4];
            acc[0][0] += av.x * wv.x; acc[0][1] += av.x * wv.y; acc[0][2] += av.x * wv.z; acc[0][3] += av.x * wv.w;
            acc[1][0] += av.y * wv.x; acc[1][1] += av.y * wv.y; acc[1][2] += av.y * wv.z; acc[1][3] += av.y * wv.w;
            acc[2][0] += av.z * wv.x; acc[2][1] += av.z * wv.y; acc[2][2] += av.z * wv.z; acc[2][3] += av.z * wv.w;
            acc[3][0] += av.w * wv.x; acc[3][1] += av.w * wv.y; acc[3][2] += av.w * wv.z; acc[3][3] += av.w * wv.w;
        }
    }
    float4 b4 = *(const float4*)(bias + n0 + tx * 4);
#pragma unroll
    for (int i = 0; i < 4; ++i) {
        const int m = m0 + ty * 4 + i;
        float4 r;
        r.x = acc[i][0] + b4.x; r.y = acc[i][1] + b4.y;
        r.z = acc[i][2] + b4.z; r.w = acc[i][3] + b4.w;
        *(float4*)(out + (size_t)m * 1536 + n0 + tx * 4) = r;
    }
}

// ---------------------------------------------------------------------------
// init: Srow[r] = sum_k Wih2[r][k]; poison-fill hstep buffers (t=0 slots -> 0)
// hsall layout: [257*1024][257*1024][3*1024][3*1024][3*1024]
// ---------------------------------------------------------------------------
__global__ __launch_bounds__(256) void k_init(
    const float* __restrict__ Wih2, float* __restrict__ Srow,
    unsigned int* __restrict__ hsall)
{
    const int g = blockIdx.x * 256 + threadIdx.x;
    if (g < 1536) {
        float s = 0.f;
        for (int k = 0; k < 128; ++k) s += Wih2[(size_t)g * 128 + k];
        Srow[g] = s;
    }
    const int NBIG = 257 * 1024;                   // 263168
    const int NTOT = 2 * NBIG + 3 * 3072;          // 535552
    for (int i = g; i < NTOT; i += gridDim.x * 256) {
        int off;
        if (i < NBIG) off = i;
        else if (i < 2 * NBIG) off = i - NBIG;
        else {
            off = i - 2 * NBIG;
            if (off >= 3072) off -= 3072;
            if (off >= 3072) off -= 3072;
        }
        hsall[i] = (off < 1024) ? 0u : POISON_U32;
    }
}

// ---------------------------------------------------------------------------
__global__ __launch_bounds__(256) void k_convpool(
    const float* __restrict__ x0, const float* __restrict__ x1,
    const float* __restrict__ cw, const float* __restrict__ cb,
    float* __restrict__ Mmax)
{
    __shared__ float hh[2][512];
    __shared__ float wsh[2][512];
    __shared__ float red[4];
    const int s = blockIdx.x >> 1, o = blockIdx.x & 1;
    const int tid = threadIdx.x;
    for (int i = tid; i < 512; i += 256) {
        hh[0][i] = x0[(size_t)(s * 2 + 1) * 512 + i];
        hh[1][i] = x1[(size_t)(s * 2 + 1) * 512 + i];
        wsh[0][i] = cw[(size_t)(o * 2 + 0) * 512 + i];
        wsh[1][i] = cw[(size_t)(o * 2 + 1) * 512 + i];
    }
    __syncthreads();
    const int p = tid;
    float acc = cb[o];
    const int base = 2 * p - 255;
#pragma unroll 1
    for (int ch = 0; ch < 2; ++ch) {
        for (int k = 0; k < 512; ++k) {
            const int pos = base + k;
            if ((unsigned)pos < 512u) acc += hh[ch][pos] * wsh[ch][k];
        }
    }
    float m = acc;
#pragma unroll
    for (int off = 32; off >= 1; off >>= 1) m = fmaxf(m, __shfl_xor(m, off, 64));
    if ((tid & 63) == 0) red[tid >> 6] = m;
    __syncthreads();
    if (tid == 0)
        Mmax[blockIdx.x] = fmaxf(fmaxf(red[0], red[1]), fmaxf(red[2], red[3]));
}

// ---------------------------------------------------------------------------
__global__ __launch_bounds__(256) void k_head(
    const float* __restrict__ xr2,
    const float* __restrict__ WA, const float* __restrict__ WB,
    const float* __restrict__ b_bi, const float* __restrict__ Wlin,
    const float* __restrict__ blin, float* __restrict__ outp)
{
    __shared__ float hA[512], hB[512];
    __shared__ float red[4];
    const int tid = threadIdx.x;
    for (int i = tid; i < 512; i += 256) {
        hA[i] = xr2[512 + i];
        hB[i] = xr2[3 * 512 + i];
    }
    __syncthreads();
    float acc = b_bi[tid];
    for (int jj = 0; jj < 512; ++jj) {
        const float a = hA[jj], b = hB[jj];
        acc += (a * b) * WA[jj * 256 + tid] + fabsf(a - b) * WB[jj * 256 + tid];
    }
    float v = tanhf(acc) * Wlin[tid];
#pragma unroll
    for (int off = 32; off >= 1; off >>= 1) v += __shfl_xor(v, off, 64);
    if ((tid & 63) == 0) red[tid >> 6] = v;
    __syncthreads();
    if (tid == 0) {
        const float ssum = red[0] + red[1] + red[2] + red[3] + blin[0];
        outp[0] = 1.f / (1.f + expf(-ssum));
    }
}

// ---------------------------------------------------------------------------
extern "C" void kernel_launch(void* const* d_in, const int* in_sizes, int n_in,
                              void* d_out, int out_size, void* d_ws, size_t ws_size,
                              hipStream_t stream)
{
    const int*   sentA = (const int*)d_in[0];
    const int*   sentB = (const int*)d_in[1];
    const float* emb   = (const float*)d_in[2];
    const float* Wih1  = (const float*)d_in[3];   // [2][1536][512]
    const float* Whh1  = (const float*)d_in[4];   // [2][1536][512]
    const float* bih1  = (const float*)d_in[5];   // [2][1536]
    const float* bhh1  = (const float*)d_in[6];   // [2][1536]
    const float* convw = (const float*)d_in[7];   // [2][2][512]
    const float* convb = (const float*)d_in[8];   // [2]
    const float* Wih2  = (const float*)d_in[9];   // [1536][128]
    const float* Whh2  = (const float*)d_in[10];  // [1536][512]
    const float* bih2  = (const float*)d_in[11];  // [1536]
    const float* bhh2  = (const float*)d_in[12];  // [1536]
    const float* WA    = (const float*)d_in[13];  // [512][256]
    const float* WB    = (const float*)d_in[14];  // [512][256]
    const float* b_bi  = (const float*)d_in[15];  // [256]
    const float* Wlin  = (const float*)d_in[16];  // [1][256]
    const float* blin  = (const float*)d_in[17];  // [1]

    float* ws = (float*)d_ws;
    size_t off = 0;
    float* gi_buf = ws + off; off += 786432;          // [2][256][1536]
    float* xout0  = ws + off; off += 262144;          // e1 L0 outputs [2][256][512]
    float* e2x    = ws + off; off += 2048;            // epoch2 input [2][2][512]
    float* xo20   = ws + off; off += 2048;
    float* xo21   = ws + off; off += 2048;
    float* xr2b   = ws + off; off += 2048;
    float* Mmax   = ws + off; off += 16;
    float* Srow   = ws + off; off += 1536;
    float* hsall  = ws + off;                         // contiguous hstep buffers
    float* hs0    = hsall;              // 257*1024
    float* hs1    = hs0 + 257 * 1024;   // 257*1024
    float* hs2    = hs1 + 257 * 1024;   // 3*1024
    float* hs3    = hs2 + 3 * 1024;
    float* hs4    = hs3 + 3 * 1024;

    const size_t WSTRIDE = (size_t)1536 * 512;

    k_init<<<256, 256, 0, stream>>>(Wih2, Srow, (unsigned int*)hsall);

    // epoch 1, layer 0
    k_gemm_gi<<<dim3(24, 8), 256, 0, stream>>>(Wih1, bih1, emb, sentA, sentB, nullptr, gi_buf);
    k_chain5<<<32, 512, 0, stream>>>(Whh1, bhh1, gi_buf,
                                     nullptr, nullptr, nullptr, nullptr, nullptr,
                                     xout0, e2x, 1024, hs0, 256, 0);
    // epoch 1, layer 1
    k_gemm_gi<<<dim3(24, 8), 256, 0, stream>>>(Wih1 + WSTRIDE, bih1 + 1536,
                                               nullptr, nullptr, nullptr, xout0, gi_buf);
    k_chain5<<<32, 512, 0, stream>>>(Whh1 + WSTRIDE, bhh1 + 1536, gi_buf,
                                     nullptr, nullptr, nullptr, nullptr, nullptr,
                                     nullptr, e2x + 512, 1024, hs1, 256, 0);
    // epoch 2, layer 0 (T=2)
    k_chain5<<<32, 512, 0, stream>>>(Whh1, bhh1, nullptr,
                                     Wih1, bih1, e2x, nullptr, nullptr,
                                     xo20, nullptr, 0, hs2, 2, 1);
    // epoch 2, layer 1 (T=2)
    k_chain5<<<32, 512, 0, stream>>>(Whh1 + WSTRIDE, bhh1 + 1536, nullptr,
                                     Wih1 + WSTRIDE, bih1 + 1536, xo20, nullptr, nullptr,
                                     xo21, nullptr, 0, hs3, 2, 1);
    // conv + degenerate max pool
    k_convpool<<<4, 256, 0, stream>>>(xo20, xo21, convw, convb, Mmax);
    // rnn_second (T=2)
    k_chain5<<<32, 512, 0, stream>>>(Whh2, bhh2, nullptr,
                                     nullptr, bih2, nullptr, Mmax, Srow,
                                     xr2b, nullptr, 0, hs4, 2, 2);
    // similarity head
    k_head<<<1, 256, 0, stream>>>(xr2b, WA, WB, b_bi, Wlin, blin, (float*)d_out);
}

// Round 6
// 1359.874 us; speedup vs baseline: 1.7926x; 1.7926x over previous
//
#include <hip/hip_runtime.h>
#include <math.h>

// ---------------------------------------------------------------------------
// Com_CNN_RNN R5: layer-pipelined chains + fused tail.
//  - k_gemm_gi: gi for epoch1-L0 only.
//  - k_pipe (64 WGs): WG 0-31 = e1-L0 (gi precomputed), WG 32-63 = e1-L1
//    skewed 1 step, gi computed on the fly (Wih slice register-resident).
//    R3's proven flag protocol (relaxed sc1 data stores -> vmcnt drain ->
//    barrier -> per-WG flag line; consumers poll flags w/ s_sleep backoff).
//  - k_tail (32 WGs): e2-L0, e2-L1, conv+maxpool, rnn2, head fused with the
//    same flag protocol between stages (weights streamed, T=2 each).
// ---------------------------------------------------------------------------

__device__ __forceinline__ float sigm(float x) { return 1.f / (1.f + expf(-x)); }

// LDS index map: p(k) = k + (k>>4)*4 (pad 4 words per 16; keeps float4 align)
#define LDSP(k) ((k) + (((k) >> 4) << 2))

__device__ __forceinline__ float red32(float v) {
    v += __shfl_xor(v, 16, 64);
    v += __shfl_xor(v, 8, 64);
    v += __shfl_xor(v, 4, 64);
    v += __shfl_xor(v, 2, 64);
    v += __shfl_xor(v, 1, 64);
    return v;
}

__device__ __forceinline__ void poll_ge(const unsigned int* p, unsigned tgt) {
    unsigned v;
    do {
        v = __hip_atomic_load(p, __ATOMIC_RELAXED, __HIP_MEMORY_SCOPE_AGENT);
        if (v < tgt) __builtin_amdgcn_s_sleep(1);
    } while (v < tgt);
}

// 256 threads stage 1024 floats global->LDS via 8B LLC loads (caller barriers)
__device__ __forceinline__ void stage1024(float* dst, const float* src, int tid) {
    if (tid < 256) {
        const unsigned long long* s = (const unsigned long long*)src + tid * 2;
        unsigned long long d0 = __hip_atomic_load(s + 0, __ATOMIC_RELAXED,
                                                  __HIP_MEMORY_SCOPE_AGENT);
        unsigned long long d1 = __hip_atomic_load(s + 1, __ATOMIC_RELAXED,
                                                  __HIP_MEMORY_SCOPE_AGENT);
        union { unsigned long long u; float2 f; } c0, c1;
        c0.u = d0; c1.u = d1;
        float* d = dst + LDSP(tid * 4);
        d[0] = c0.f.x; d[1] = c0.f.y; d[2] = c1.f.x; d[3] = c1.f.y;
    }
}

__device__ __forceinline__ float gru1(float gr, float gz, float gn,
                                      float ar, float az, float an,
                                      const float bh[3], float hp) {
    float r = sigm(gr + ar + bh[0]);
    float z = sigm(gz + az + bh[1]);
    float n = tanhf(gn + r * (an + bh[2]));
    return (1.f - z) * n + z * hp;
}

// ---------------------------------------------------------------------------
// k_pipe: epoch-1 L0 + L1 pipelined. grid 64 x 512.
// ---------------------------------------------------------------------------
__global__ __launch_bounds__(512, 1) void k_pipe(
    const float* __restrict__ Whh1, const float* __restrict__ bhh1,
    const float* __restrict__ Wih1, const float* __restrict__ bih1,
    const float* __restrict__ gi0,        // [2][256][1536] (L0 only)
    float* __restrict__ e2x,              // [2 sent][2 layer][512]
    float* __restrict__ hbuf0,            // [257][2][512]
    float* __restrict__ hbuf1,            // [257][2][512]
    unsigned int* __restrict__ fL0,       // [32][16]
    unsigned int* __restrict__ fL1)       // [32][16]
{
    const int tid   = threadIdx.x;
    const int layer = blockIdx.x >> 5;    // 0 or 1
    const int wgi   = blockIdx.x & 31;
    const int grp   = tid >> 5;           // 0..15
    const int lane  = tid & 31;
    const int j     = wgi * 16 + grp;     // h row 0..511
    const int colbase = lane * 16;

    __shared__ float xlds[1280];
    __shared__ float hlds[1280];

    const size_t WS = (size_t)1536 * 512;
    const float* WH = Whh1 + (size_t)layer * WS;

    // recurrent weights resident
    float wh[3][16];
#pragma unroll
    for (int q = 0; q < 3; ++q) {
        const float* src = WH + (size_t)(q * 512 + j) * 512 + colbase;
#pragma unroll
        for (int c4 = 0; c4 < 4; ++c4) {
            float4 v = *(const float4*)(src + c4 * 4);
            wh[q][c4*4+0] = v.x; wh[q][c4*4+1] = v.y;
            wh[q][c4*4+2] = v.z; wh[q][c4*4+3] = v.w;
        }
    }
#pragma unroll
    for (int q = 0; q < 3; ++q)
#pragma unroll
        for (int c = 0; c < 16; ++c)
            asm volatile("" : "+v"(wh[q][c]));

    float bh[3];
#pragma unroll
    for (int q = 0; q < 3; ++q) bh[q] = bhh1[layer * 1536 + q * 512 + j];

    float hprev[2] = {0.f, 0.f};

    if (layer == 0) {
        // ------------------------- L0 -------------------------
        for (int t = 1; t <= 256; ++t) {
            float g0[3][2];
#pragma unroll
            for (int q = 0; q < 3; ++q)
#pragma unroll
                for (int s = 0; s < 2; ++s)
                    g0[q][s] = gi0[((size_t)(s * 256 + t - 1)) * 1536 + q * 512 + j];

            float acc[3][2] = {{0.f,0.f},{0.f,0.f},{0.f,0.f}};
            if (t > 1) {
                if (tid < 32) poll_ge(fL0 + tid * 16, (unsigned)(t - 1));
                __syncthreads();
                stage1024(xlds, hbuf0 + (size_t)(t - 1) * 1024, tid);
                __syncthreads();
#pragma unroll
                for (int s = 0; s < 2; ++s) {
                    const int base = s * 640 + 20 * lane;
#pragma unroll
                    for (int c4 = 0; c4 < 4; ++c4) {
                        float4 hv = *(const float4*)&xlds[base + c4 * 4];
#pragma unroll
                        for (int q = 0; q < 3; ++q)
                            acc[q][s] += wh[q][c4*4+0]*hv.x + wh[q][c4*4+1]*hv.y
                                       + wh[q][c4*4+2]*hv.z + wh[q][c4*4+3]*hv.w;
                    }
                }
#pragma unroll
                for (int q = 0; q < 3; ++q)
#pragma unroll
                    for (int s = 0; s < 2; ++s) acc[q][s] = red32(acc[q][s]);
            }

            float hn[2];
#pragma unroll
            for (int s = 0; s < 2; ++s) {
                hn[s] = gru1(g0[0][s], g0[1][s], g0[2][s],
                             acc[0][s], acc[1][s], acc[2][s], bh, hprev[s]);
                hprev[s] = hn[s];
            }
            if (lane == 0) {
#pragma unroll
                for (int s = 0; s < 2; ++s) {
                    __hip_atomic_store(hbuf0 + (size_t)t * 1024 + s * 512 + j, hn[s],
                                       __ATOMIC_RELAXED, __HIP_MEMORY_SCOPE_AGENT);
                    if (t == 256) e2x[s * 1024 + j] = hn[s];
                }
            }
            __builtin_amdgcn_s_waitcnt(0);
            __syncthreads();
            if (tid == 0)
                __hip_atomic_store(fL0 + wgi * 16, (unsigned)t,
                                   __ATOMIC_RELAXED, __HIP_MEMORY_SCOPE_AGENT);
        }
    } else {
        // ------------------------- L1 (skewed by 1 step) -------------------------
        const float* WI = Wih1 + WS;
        float wi[3][16];
#pragma unroll
        for (int q = 0; q < 3; ++q) {
            const float* src = WI + (size_t)(q * 512 + j) * 512 + colbase;
#pragma unroll
            for (int c4 = 0; c4 < 4; ++c4) {
                float4 v = *(const float4*)(src + c4 * 4);
                wi[q][c4*4+0] = v.x; wi[q][c4*4+1] = v.y;
                wi[q][c4*4+2] = v.z; wi[q][c4*4+3] = v.w;
            }
        }
#pragma unroll
        for (int q = 0; q < 3; ++q)
#pragma unroll
            for (int c = 0; c < 16; ++c)
                asm volatile("" : "+v"(wi[q][c]));

        float bi[3];
#pragma unroll
        for (int q = 0; q < 3; ++q) bi[q] = bih1[1536 + q * 512 + j];

        for (int t = 1; t <= 256; ++t) {
            if (tid < 32) poll_ge(fL0 + tid * 16, (unsigned)t);
            else if (t > 1 && tid >= 64 && tid < 96)
                poll_ge(fL1 + (tid - 64) * 16, (unsigned)(t - 1));
            __syncthreads();
            stage1024(xlds, hbuf0 + (size_t)t * 1024, tid);
            if (t > 1 && tid >= 256 && tid < 512) {
                const int i = tid - 256;
                const unsigned long long* s =
                    (const unsigned long long*)(hbuf1 + (size_t)(t - 1) * 1024) + i * 2;
                unsigned long long d0 = __hip_atomic_load(s + 0, __ATOMIC_RELAXED,
                                                          __HIP_MEMORY_SCOPE_AGENT);
                unsigned long long d1 = __hip_atomic_load(s + 1, __ATOMIC_RELAXED,
                                                          __HIP_MEMORY_SCOPE_AGENT);
                union { unsigned long long u; float2 f; } c0, c1;
                c0.u = d0; c1.u = d1;
                float* d = hlds + LDSP(i * 4);
                d[0] = c0.f.x; d[1] = c0.f.y; d[2] = c1.f.x; d[3] = c1.f.y;
            }
            __syncthreads();

            // combined accumulators: r,z get gi+gh summed; n kept separate
            float aR[2] = {0.f,0.f}, aZ[2] = {0.f,0.f};
            float aGN[2] = {0.f,0.f}, aHN[2] = {0.f,0.f};
#pragma unroll
            for (int s = 0; s < 2; ++s) {
                const int base = s * 640 + 20 * lane;
#pragma unroll
                for (int c4 = 0; c4 < 4; ++c4) {
                    float4 xv = *(const float4*)&xlds[base + c4 * 4];
                    aR[s]  += wi[0][c4*4+0]*xv.x + wi[0][c4*4+1]*xv.y
                            + wi[0][c4*4+2]*xv.z + wi[0][c4*4+3]*xv.w;
                    aZ[s]  += wi[1][c4*4+0]*xv.x + wi[1][c4*4+1]*xv.y
                            + wi[1][c4*4+2]*xv.z + wi[1][c4*4+3]*xv.w;
                    aGN[s] += wi[2][c4*4+0]*xv.x + wi[2][c4*4+1]*xv.y
                            + wi[2][c4*4+2]*xv.z + wi[2][c4*4+3]*xv.w;
                }
                if (t > 1) {
#pragma unroll
                    for (int c4 = 0; c4 < 4; ++c4) {
                        float4 hv = *(const float4*)&hlds[base + c4 * 4];
                        aR[s]  += wh[0][c4*4+0]*hv.x + wh[0][c4*4+1]*hv.y
                                + wh[0][c4*4+2]*hv.z + wh[0][c4*4+3]*hv.w;
                        aZ[s]  += wh[1][c4*4+0]*hv.x + wh[1][c4*4+1]*hv.y
                                + wh[1][c4*4+2]*hv.z + wh[1][c4*4+3]*hv.w;
                        aHN[s] += wh[2][c4*4+0]*hv.x + wh[2][c4*4+1]*hv.y
                                + wh[2][c4*4+2]*hv.z + wh[2][c4*4+3]*hv.w;
                    }
                }
            }
#pragma unroll
            for (int s = 0; s < 2; ++s) {
                aR[s] = red32(aR[s]); aZ[s] = red32(aZ[s]);
                aGN[s] = red32(aGN[s]); aHN[s] = red32(aHN[s]);
            }

            float hn[2];
#pragma unroll
            for (int s = 0; s < 2; ++s) {
                float r = sigm(aR[s] + bi[0] + bh[0]);
                float z = sigm(aZ[s] + bi[1] + bh[1]);
                float n = tanhf(aGN[s] + bi[2] + r * (aHN[s] + bh[2]));
                hn[s] = (1.f - z) * n + z * hprev[s];
                hprev[s] = hn[s];
            }
            if (lane == 0) {
#pragma unroll
                for (int s = 0; s < 2; ++s) {
                    __hip_atomic_store(hbuf1 + (size_t)t * 1024 + s * 512 + j, hn[s],
                                       __ATOMIC_RELAXED, __HIP_MEMORY_SCOPE_AGENT);
                    if (t == 256) e2x[s * 1024 + 512 + j] = hn[s];
                }
            }
            __builtin_amdgcn_s_waitcnt(0);
            __syncthreads();
            if (tid == 0)
                __hip_atomic_store(fL1 + wgi * 16, (unsigned)t,
                                   __ATOMIC_RELAXED, __HIP_MEMORY_SCOPE_AGENT);
        }
    }
}

// ---------------------------------------------------------------------------
// k_tail: e2-L0 -> e2-L1 -> conv+pool -> rnn2 -> head, fused. grid 32 x 512.
// ---------------------------------------------------------------------------
__global__ __launch_bounds__(512, 1) void k_tail(
    const float* __restrict__ Wih1, const float* __restrict__ bih1,
    const float* __restrict__ Whh1, const float* __restrict__ bhh1,
    const float* __restrict__ convw, const float* __restrict__ convb,
    const float* __restrict__ Whh2, const float* __restrict__ bhh2,
    const float* __restrict__ bih2, const float* __restrict__ Srow,
    const float* __restrict__ e2x,
    const float* __restrict__ WA, const float* __restrict__ WB,
    const float* __restrict__ b_bi, const float* __restrict__ Wlin,
    const float* __restrict__ blin,
    float* __restrict__ tb0, float* __restrict__ tb1, float* __restrict__ tr,
    float* __restrict__ Mmax,
    unsigned int* __restrict__ tctr, unsigned int* __restrict__ mf,
    float* __restrict__ outp)
{
    const int tid = threadIdx.x;
    const int wgi = blockIdx.x;
    const int grp = tid >> 5, lane = tid & 31;
    const int j = wgi * 16 + grp, colbase = lane * 16;
    const size_t WS = (size_t)1536 * 512;

    __shared__ float xlds[1280];
    __shared__ float hlds[1280];
    __shared__ float red[8];
    __shared__ float smax[4];

#define WAIT_ALL(val)  do { if (tid < 32) poll_ge(tctr + tid * 16, (unsigned)(val)); \
                            __syncthreads(); } while (0)
#define PUBLISH(val)   do { __builtin_amdgcn_s_waitcnt(0); __syncthreads(); \
                            if (tid == 0) __hip_atomic_store(tctr + wgi * 16, (unsigned)(val), \
                                __ATOMIC_RELAXED, __HIP_MEMORY_SCOPE_AGENT); } while (0)

    // -------- stage e2x into LDS (plain loads; written by previous dispatch)
    if (tid < 256) {
        const int i = tid * 4, s = i >> 9, k = i & 511;
        float4 v = *(const float4*)(e2x + s * 1024 + k);        // timestep 0
        float* d = xlds + LDSP(i);
        d[0] = v.x; d[1] = v.y; d[2] = v.z; d[3] = v.w;
    } else {
        const int i = (tid - 256) * 4, s = i >> 9, k = i & 511;
        float4 v = *(const float4*)(e2x + s * 1024 + 512 + k);  // timestep 1
        float* d = hlds + LDSP(i);
        d[0] = v.x; d[1] = v.y; d[2] = v.z; d[3] = v.w;
    }
    __syncthreads();

    // ================= stage A: e2-L0 =================
    float gp[2][2][3];   // [t][s][q]
    float bh[3], hp[2];
#pragma unroll
    for (int q = 0; q < 3; ++q) {
        const float* wp = Wih1 + (size_t)(q * 512 + j) * 512 + colbase;
        float w16[16];
#pragma unroll
        for (int c4 = 0; c4 < 4; ++c4) {
            float4 v = *(const float4*)(wp + c4 * 4);
            w16[c4*4+0] = v.x; w16[c4*4+1] = v.y; w16[c4*4+2] = v.z; w16[c4*4+3] = v.w;
        }
        float d00 = 0.f, d01 = 0.f, d10 = 0.f, d11 = 0.f;
#pragma unroll
        for (int c = 0; c < 16; ++c) {
            const int b0 = 20 * lane + ((colbase + c) & 15) + 0;   // placeholder
            (void)b0;
        }
        // dots against staged x (t0 in xlds, t1 in hlds)
#pragma unroll
        for (int c4 = 0; c4 < 4; ++c4) {
            float4 x0 = *(const float4*)&xlds[0 * 640 + 20 * lane + c4 * 4];
            float4 x1 = *(const float4*)&xlds[1 * 640 + 20 * lane + c4 * 4];
            float4 y0 = *(const float4*)&hlds[0 * 640 + 20 * lane + c4 * 4];
            float4 y1 = *(const float4*)&hlds[1 * 640 + 20 * lane + c4 * 4];
            d00 += w16[c4*4+0]*x0.x + w16[c4*4+1]*x0.y + w16[c4*4+2]*x0.z + w16[c4*4+3]*x0.w;
            d01 += w16[c4*4+0]*x1.x + w16[c4*4+1]*x1.y + w16[c4*4+2]*x1.z + w16[c4*4+3]*x1.w;
            d10 += w16[c4*4+0]*y0.x + w16[c4*4+1]*y0.y + w16[c4*4+2]*y0.z + w16[c4*4+3]*y0.w;
            d11 += w16[c4*4+0]*y1.x + w16[c4*4+1]*y1.y + w16[c4*4+2]*y1.z + w16[c4*4+3]*y1.w;
        }
        const float biq = bih1[q * 512 + j];
        gp[0][0][q] = red32(d00) + biq; gp[0][1][q] = red32(d01) + biq;
        gp[1][0][q] = red32(d10) + biq; gp[1][1][q] = red32(d11) + biq;
    }
#pragma unroll
    for (int q = 0; q < 3; ++q) bh[q] = bhh1[q * 512 + j];

    // step 1 (h0 = 0)
#pragma unroll
    for (int s = 0; s < 2; ++s)
        hp[s] = gru1(gp[0][s][0], gp[0][s][1], gp[0][s][2], 0.f, 0.f, 0.f, bh, 0.f);
    if (lane == 0)
#pragma unroll
        for (int s = 0; s < 2; ++s)
            __hip_atomic_store(tb0 + 1024 + s * 512 + j, hp[s],
                               __ATOMIC_RELAXED, __HIP_MEMORY_SCOPE_AGENT);
    PUBLISH(1);

    // step 2
    WAIT_ALL(1);
    stage1024(hlds, tb0 + 1024, tid);
    __syncthreads();
    {
        float wh3[3][16];
#pragma unroll
        for (int q = 0; q < 3; ++q) {
            const float* wp = Whh1 + (size_t)(q * 512 + j) * 512 + colbase;
#pragma unroll
            for (int c4 = 0; c4 < 4; ++c4) {
                float4 v = *(const float4*)(wp + c4 * 4);
                wh3[q][c4*4+0] = v.x; wh3[q][c4*4+1] = v.y;
                wh3[q][c4*4+2] = v.z; wh3[q][c4*4+3] = v.w;
            }
        }
        float acc[3][2] = {{0.f,0.f},{0.f,0.f},{0.f,0.f}};
#pragma unroll
        for (int s = 0; s < 2; ++s) {
            const int base = s * 640 + 20 * lane;
#pragma unroll
            for (int c4 = 0; c4 < 4; ++c4) {
                float4 hv = *(const float4*)&hlds[base + c4 * 4];
#pragma unroll
                for (int q = 0; q < 3; ++q)
                    acc[q][s] += wh3[q][c4*4+0]*hv.x + wh3[q][c4*4+1]*hv.y
                               + wh3[q][c4*4+2]*hv.z + wh3[q][c4*4+3]*hv.w;
            }
        }
#pragma unroll
        for (int s = 0; s < 2; ++s) {
            float a0 = red32(acc[0][s]), a1 = red32(acc[1][s]), a2 = red32(acc[2][s]);
            hp[s] = gru1(gp[1][s][0], gp[1][s][1], gp[1][s][2], a0, a1, a2, bh, hp[s]);
        }
        if (lane == 0)
#pragma unroll
            for (int s = 0; s < 2; ++s)
                __hip_atomic_store(tb0 + 2048 + s * 512 + j, hp[s],
                                   __ATOMIC_RELAXED, __HIP_MEMORY_SCOPE_AGENT);
        PUBLISH(2);
    }

    // ================= stage B: e2-L1 =================
    WAIT_ALL(2);
    stage1024(xlds, tb0 + 1024, tid);          // x step0 = L0 h1
    if (tid >= 256) {
        const int i = tid - 256;
        const unsigned long long* s = (const unsigned long long*)(tb0 + 2048) + i * 2;
        unsigned long long d0 = __hip_atomic_load(s + 0, __ATOMIC_RELAXED, __HIP_MEMORY_SCOPE_AGENT);
        unsigned long long d1 = __hip_atomic_load(s + 1, __ATOMIC_RELAXED, __HIP_MEMORY_SCOPE_AGENT);
        union { unsigned long long u; float2 f; } c0, c1; c0.u = d0; c1.u = d1;
        float* d = hlds + LDSP(i * 4);
        d[0] = c0.f.x; d[1] = c0.f.y; d[2] = c1.f.x; d[3] = c1.f.y;
    }
    __syncthreads();
#pragma unroll
    for (int q = 0; q < 3; ++q) {
        const float* wp = Wih1 + WS + (size_t)(q * 512 + j) * 512 + colbase;
        float w16[16];
#pragma unroll
        for (int c4 = 0; c4 < 4; ++c4) {
            float4 v = *(const float4*)(wp + c4 * 4);
            w16[c4*4+0] = v.x; w16[c4*4+1] = v.y; w16[c4*4+2] = v.z; w16[c4*4+3] = v.w;
        }
        float d00 = 0.f, d01 = 0.f, d10 = 0.f, d11 = 0.f;
#pragma unroll
        for (int c4 = 0; c4 < 4; ++c4) {
            float4 x0 = *(const float4*)&xlds[0 * 640 + 20 * lane + c4 * 4];
            float4 x1 = *(const float4*)&xlds[1 * 640 + 20 * lane + c4 * 4];
            float4 y0 = *(const float4*)&hlds[0 * 640 + 20 * lane + c4 * 4];
            float4 y1 = *(const float4*)&hlds[1 * 640 + 20 * lane + c4 * 4];
            d00 += w16[c4*4+0]*x0.x + w16[c4*4+1]*x0.y + w16[c4*4+2]*x0.z + w16[c4*4+3]*x0.w;
            d01 += w16[c4*4+0]*x1.x + w16[c4*4+1]*x1.y + w16[c4*4+2]*x1.z + w16[c4*4+3]*x1.w;
            d10 += w16[c4*4+0]*y0.x + w16[c4*4+1]*y0.y + w16[c4*4+2]*y0.z + w16[c4*4+3]*y0.w;
            d11 += w16[c4*4+0]*y1.x + w16[c4*4+1]*y1.y + w16[c4*4+2]*y1.z + w16[c4*4+3]*y1.w;
        }
        const float biq = bih1[1536 + q * 512 + j];
        gp[0][0][q] = red32(d00) + biq; gp[0][1][q] = red32(d01) + biq;
        gp[1][0][q] = red32(d10) + biq; gp[1][1][q] = red32(d11) + biq;
    }
#pragma unroll
    for (int q = 0; q < 3; ++q) bh[q] = bhh1[1536 + q * 512 + j];

#pragma unroll
    for (int s = 0; s < 2; ++s)
        hp[s] = gru1(gp[0][s][0], gp[0][s][1], gp[0][s][2], 0.f, 0.f, 0.f, bh, 0.f);
    if (lane == 0)
#pragma unroll
        for (int s = 0; s < 2; ++s)
            __hip_atomic_store(tb1 + 1024 + s * 512 + j, hp[s],
                               __ATOMIC_RELAXED, __HIP_MEMORY_SCOPE_AGENT);
    PUBLISH(3);

    WAIT_ALL(3);
    stage1024(hlds, tb1 + 1024, tid);
    __syncthreads();
    {
        float wh3[3][16];
#pragma unroll
        for (int q = 0; q < 3; ++q) {
            const float* wp = Whh1 + WS + (size_t)(q * 512 + j) * 512 + colbase;
#pragma unroll
            for (int c4 = 0; c4 < 4; ++c4) {
                float4 v = *(const float4*)(wp + c4 * 4);
                wh3[q][c4*4+0] = v.x; wh3[q][c4*4+1] = v.y;
                wh3[q][c4*4+2] = v.z; wh3[q][c4*4+3] = v.w;
            }
        }
        float acc[3][2] = {{0.f,0.f},{0.f,0.f},{0.f,0.f}};
#pragma unroll
        for (int s = 0; s < 2; ++s) {
            const int base = s * 640 + 20 * lane;
#pragma unroll
            for (int c4 = 0; c4 < 4; ++c4) {
                float4 hv = *(const float4*)&hlds[base + c4 * 4];
#pragma unroll
                for (int q = 0; q < 3; ++q)
                    acc[q][s] += wh3[q][c4*4+0]*hv.x + wh3[q][c4*4+1]*hv.y
                               + wh3[q][c4*4+2]*hv.z + wh3[q][c4*4+3]*hv.w;
            }
        }
#pragma unroll
        for (int s = 0; s < 2; ++s) {
            float a0 = red32(acc[0][s]), a1 = red32(acc[1][s]), a2 = red32(acc[2][s]);
            hp[s] = gru1(gp[1][s][0], gp[1][s][1], gp[1][s][2], a0, a1, a2, bh, hp[s]);
        }
        if (lane == 0)
#pragma unroll
            for (int s = 0; s < 2; ++s)
                __hip_atomic_store(tb1 + 2048 + s * 512 + j, hp[s],
                                   __ATOMIC_RELAXED, __HIP_MEMORY_SCOPE_AGENT);
        PUBLISH(4);
    }

    // ================= stage C: conv + global max pool =================
    WAIT_ALL(4);
    float m4[4];
    if (wgi == 0) {
        stage1024(xlds, tb0 + 2048, tid);          // finals L0 [2][512]
        if (tid >= 256) {
            const int i = tid - 256;
            const unsigned long long* s = (const unsigned long long*)(tb1 + 2048) + i * 2;
            unsigned long long d0 = __hip_atomic_load(s + 0, __ATOMIC_RELAXED, __HIP_MEMORY_SCOPE_AGENT);
            unsigned long long d1 = __hip_atomic_load(s + 1, __ATOMIC_RELAXED, __HIP_MEMORY_SCOPE_AGENT);
            union { unsigned long long u; float2 f; } c0, c1; c0.u = d0; c1.u = d1;
            float* d = hlds + LDSP(i * 4);
            d[0] = c0.f.x; d[1] = c0.f.y; d[2] = c1.f.x; d[3] = c1.f.y;
        }
        __syncthreads();
        for (int so = 0; so < 4; ++so) {
            const int s = so >> 1, o = so & 1;
            float acc = -3.4e38f;
            if (tid < 256) {
                acc = convb[o];
                const int base = 2 * tid - 255;
                for (int k = 0; k < 512; ++k) {
                    const int pos = base + k;
                    if ((unsigned)pos < 512u) {
                        const int gi0i = s * 512 + pos;
                        acc += xlds[LDSP(gi0i)] * convw[(size_t)(o * 2 + 0) * 512 + k]
                             + hlds[LDSP(gi0i)] * convw[(size_t)(o * 2 + 1) * 512 + k];
                    }
                }
            }
            float m = acc;
            m = fmaxf(m, __shfl_xor(m, 32, 64));
            m = fmaxf(m, __shfl_xor(m, 16, 64));
            m = fmaxf(m, __shfl_xor(m, 8, 64));
            m = fmaxf(m, __shfl_xor(m, 4, 64));
            m = fmaxf(m, __shfl_xor(m, 2, 64));
            m = fmaxf(m, __shfl_xor(m, 1, 64));
            if ((tid & 63) == 0) red[tid >> 6] = m;
            __syncthreads();
            if (tid == 0) {
                float mm = red[0];
                for (int i = 1; i < 8; ++i) mm = fmaxf(mm, red[i]);
                smax[so] = mm;
            }
            __syncthreads();
        }
        if (tid == 0) {
            for (int i = 0; i < 4; ++i)
                __hip_atomic_store(Mmax + i, smax[i],
                                   __ATOMIC_RELAXED, __HIP_MEMORY_SCOPE_AGENT);
            __builtin_amdgcn_s_waitcnt(0);
            __hip_atomic_store(mf, 1u, __ATOMIC_RELAXED, __HIP_MEMORY_SCOPE_AGENT);
        }
        __syncthreads();
#pragma unroll
        for (int i = 0; i < 4; ++i) m4[i] = smax[i];
    } else {
        if (tid == 0) poll_ge(mf, 1u);
        __syncthreads();
#pragma unroll
        for (int i = 0; i < 4; ++i)
            m4[i] = __hip_atomic_load((const float*)Mmax + i, __ATOMIC_RELAXED,
                                      __HIP_MEMORY_SCOPE_AGENT);
    }

    // ================= stage D: rnn2 (T=2, gi = Mmax*Srow + bih2) =================
    {
        float wh3[3][16];
#pragma unroll
        for (int q = 0; q < 3; ++q) {
            const float* wp = Whh2 + (size_t)(q * 512 + j) * 512 + colbase;
#pragma unroll
            for (int c4 = 0; c4 < 4; ++c4) {
                float4 v = *(const float4*)(wp + c4 * 4);
                wh3[q][c4*4+0] = v.x; wh3[q][c4*4+1] = v.y;
                wh3[q][c4*4+2] = v.z; wh3[q][c4*4+3] = v.w;
            }
        }
#pragma unroll
        for (int q = 0; q < 3; ++q) {
            const float sq = Srow[q * 512 + j];
            const float biq = bih2[q * 512 + j];
#pragma unroll
            for (int s = 0; s < 2; ++s) {
                gp[0][s][q] = m4[s * 2 + 0] * sq + biq;
                gp[1][s][q] = m4[s * 2 + 1] * sq + biq;
            }
            bh[q] = bhh2[q * 512 + j];
        }
#pragma unroll
        for (int s = 0; s < 2; ++s)
            hp[s] = gru1(gp[0][s][0], gp[0][s][1], gp[0][s][2], 0.f, 0.f, 0.f, bh, 0.f);
        if (lane == 0)
#pragma unroll
            for (int s = 0; s < 2; ++s)
                __hip_atomic_store(tr + 1024 + s * 512 + j, hp[s],
                                   __ATOMIC_RELAXED, __HIP_MEMORY_SCOPE_AGENT);
        PUBLISH(5);

        WAIT_ALL(5);
        stage1024(hlds, tr + 1024, tid);
        __syncthreads();
        float acc[3][2] = {{0.f,0.f},{0.f,0.f},{0.f,0.f}};
#pragma unroll
        for (int s = 0; s < 2; ++s) {
            const int base = s * 640 + 20 * lane;
#pragma unroll
            for (int c4 = 0; c4 < 4; ++c4) {
                float4 hv = *(const float4*)&hlds[base + c4 * 4];
#pragma unroll
                for (int q = 0; q < 3; ++q)
                    acc[q][s] += wh3[q][c4*4+0]*hv.x + wh3[q][c4*4+1]*hv.y
                               + wh3[q][c4*4+2]*hv.z + wh3[q][c4*4+3]*hv.w;
            }
        }
#pragma unroll
        for (int s = 0; s < 2; ++s) {
            float a0 = red32(acc[0][s]), a1 = red32(acc[1][s]), a2 = red32(acc[2][s]);
            hp[s] = gru1(gp[1][s][0], gp[1][s][1], gp[1][s][2], a0, a1, a2, bh, hp[s]);
        }
        if (lane == 0)
#pragma unroll
            for (int s = 0; s < 2; ++s)
                __hip_atomic_store(tr + 2048 + s * 512 + j, hp[s],
                                   __ATOMIC_RELAXED, __HIP_MEMORY_SCOPE_AGENT);
        PUBLISH(6);
    }

    // ================= stage E: similarity head (WG0 only) =================
    WAIT_ALL(6);
    if (wgi != 0) return;
    stage1024(xlds, tr + 2048, tid);          // hA = [0..511], hB = [512..1023]
    __syncthreads();
    float v = 0.f;
    if (tid < 256) {
        float acc = b_bi[tid];
        for (int jj = 0; jj < 512; ++jj) {
            const float a = xlds[LDSP(jj)];
            const float b = xlds[LDSP(512 + jj)];
            acc += (a * b) * WA[(size_t)jj * 256 + tid]
                 + fabsf(a - b) * WB[(size_t)jj * 256 + tid];
        }
        v = tanhf(acc) * Wlin[tid];
    }
    v += __shfl_xor(v, 32, 64);
    v += __shfl_xor(v, 16, 64);
    v += __shfl_xor(v, 8, 64);
    v += __shfl_xor(v, 4, 64);
    v += __shfl_xor(v, 2, 64);
    v += __shfl_xor(v, 1, 64);
    if ((tid & 63) == 0) red[tid >> 6] = v;
    __syncthreads();
    if (tid == 0) {
        float ssum = blin[0];
        for (int i = 0; i < 8; ++i) ssum += red[i];
        outp[0] = 1.f / (1.f + expf(-ssum));
    }
#undef WAIT_ALL
#undef PUBLISH
}

// ---------------------------------------------------------------------------
// gi GEMM (L0 only): out[m][n] = sum_k A[m][k]*W[n][k] + bias[n]
// ---------------------------------------------------------------------------
__global__ __launch_bounds__(256, 2) void k_gemm_gi(
    const float* __restrict__ W, const float* __restrict__ bias,
    const float* __restrict__ emb, const int* __restrict__ sentA,
    const int* __restrict__ sentB, float* __restrict__ out)
{
    __shared__ float At[32][68];
    __shared__ float Wt[32][68];
    const int tid = threadIdx.x;
    const int n0 = blockIdx.x * 64;
    const int m0 = blockIdx.y * 64;
    const int lrow = tid >> 3, lc4 = tid & 7;

    const int ma = m0 + lrow, mb = ma + 32;
    const int ia = (ma < 256) ? sentA[ma & 255] : sentB[ma & 255];
    const int ib = (mb < 256) ? sentA[mb & 255] : sentB[mb & 255];
    const float* ar0 = emb + (size_t)ia * 512;
    const float* ar1 = emb + (size_t)ib * 512;
    const float* wr0 = W + (size_t)(n0 + lrow) * 512;
    const float* wr1 = wr0 + (size_t)32 * 512;

    const int ty = tid >> 4, tx = tid & 15;
    float acc[4][4];
#pragma unroll
    for (int i = 0; i < 4; ++i)
#pragma unroll
        for (int jj = 0; jj < 4; ++jj) acc[i][jj] = 0.f;

    for (int kk = 0; kk < 512; kk += 32) {
        float4 a0 = *(const float4*)(ar0 + kk + lc4 * 4);
        float4 a1 = *(const float4*)(ar1 + kk + lc4 * 4);
        float4 w0 = *(const float4*)(wr0 + kk + lc4 * 4);
        float4 w1 = *(const float4*)(wr1 + kk + lc4 * 4);
        __syncthreads();
        const int kb = lc4 * 4;
        At[kb+0][lrow] = a0.x; At[kb+1][lrow] = a0.y; At[kb+2][lrow] = a0.z; At[kb+3][lrow] = a0.w;
        At[kb+0][lrow+32] = a1.x; At[kb+1][lrow+32] = a1.y; At[kb+2][lrow+32] = a1.z; At[kb+3][lrow+32] = a1.w;
        Wt[kb+0][lrow] = w0.x; Wt[kb+1][lrow] = w0.y; Wt[kb+2][lrow] = w0.z; Wt[kb+3][lrow] = w0.w;
        Wt[kb+0][lrow+32] = w1.x; Wt[kb+1][lrow+32] = w1.y; Wt[kb+2][lrow+32] = w1.z; Wt[kb+3][lrow+32] = w1.w;
        __syncthreads();
#pragma unroll
        for (int k = 0; k < 32; ++k) {
            float4 av = *(const float4*)&At[k][ty * 4];
            float4 wv = *(const float4*)&Wt[k][tx * 4];
            acc[0][0] += av.x * wv.x; acc[0][1] += av.x * wv.y; acc[0][2] += av.x * wv.z; acc[0][3] += av.x * wv.w;
            acc[1][0] += av.y * wv.x; acc[1][1] += av.y * wv.y; acc[1][2] += av.y * wv.z; acc[1][3] += av.y * wv.w;
            acc[2][0] += av.z * wv.x; acc[2][1] += av.z * wv.y; acc[2][2] += av.z * wv.z; acc[2][3] += av.z * wv.w;
            acc[3][0] += av.w * wv.x; acc[3][1] += av.w * wv.y; acc[3][2] += av.w * wv.z; acc[3][3] += av.w * wv.w;
        }
    }
    float4 b4 = *(const float4*)(bias + n0 + tx * 4);
#pragma unroll
    for (int i = 0; i < 4; ++i) {
        const int m = m0 + ty * 4 + i;
        float4 r;
        r.x = acc[i][0] + b4.x; r.y = acc[i][1] + b4.y;
        r.z = acc[i][2] + b4.z; r.w = acc[i][3] + b4.w;
        *(float4*)(out + (size_t)m * 1536 + n0 + tx * 4) = r;
    }
}

// ---------------------------------------------------------------------------
// init: zero all flag lines; Srow[r] = sum_k Wih2[r][k] (k<128)
// ---------------------------------------------------------------------------
__global__ __launch_bounds__(256) void k_init(
    const float* __restrict__ Wih2, float* __restrict__ Srow,
    unsigned int* __restrict__ flags)   // fL0|fL1|tctr|mf = 512+512+512+16
{
    const int g = blockIdx.x * 256 + threadIdx.x;   // 0..2047
    if (g < 1536) {
        float s = 0.f;
        for (int k = 0; k < 128; ++k) s += Wih2[(size_t)g * 128 + k];
        Srow[g] = s;
    }
    if (g < 1552) flags[g] = 0u;
}

// ---------------------------------------------------------------------------
extern "C" void kernel_launch(void* const* d_in, const int* in_sizes, int n_in,
                              void* d_out, int out_size, void* d_ws, size_t ws_size,
                              hipStream_t stream)
{
    const int*   sentA = (const int*)d_in[0];
    const int*   sentB = (const int*)d_in[1];
    const float* emb   = (const float*)d_in[2];
    const float* Wih1  = (const float*)d_in[3];   // [2][1536][512]
    const float* Whh1  = (const float*)d_in[4];   // [2][1536][512]
    const float* bih1  = (const float*)d_in[5];   // [2][1536]
    const float* bhh1  = (const float*)d_in[6];   // [2][1536]
    const float* convw = (const float*)d_in[7];   // [2][2][512]
    const float* convb = (const float*)d_in[8];   // [2]
    const float* Wih2  = (const float*)d_in[9];   // [1536][128]
    const float* Whh2  = (const float*)d_in[10];  // [1536][512]
    const float* bih2  = (const float*)d_in[11];  // [1536]
    const float* bhh2  = (const float*)d_in[12];  // [1536]
    const float* WA    = (const float*)d_in[13];  // [512][256]
    const float* WB    = (const float*)d_in[14];  // [512][256]
    const float* b_bi  = (const float*)d_in[15];  // [256]
    const float* Wlin  = (const float*)d_in[16];  // [1][256]
    const float* blin  = (const float*)d_in[17];  // [1]

    float* ws = (float*)d_ws;
    size_t off = 0;
    float* gi_buf = ws + off; off += 786432;      // [2][256][1536]
    float* e2x    = ws + off; off += 2048;        // [2 sent][2 layer][512]
    float* hbuf0  = ws + off; off += 257 * 1024;
    float* hbuf1  = ws + off; off += 257 * 1024;
    float* tb0    = ws + off; off += 3 * 1024;
    float* tb1    = ws + off; off += 3 * 1024;
    float* tr     = ws + off; off += 3 * 1024;
    float* Mmax   = ws + off; off += 16;
    float* Srow   = ws + off; off += 1536;
    unsigned int* flags = (unsigned int*)(ws + off);  // 1552 u32
    unsigned int* fL0  = flags;
    unsigned int* fL1  = flags + 512;
    unsigned int* tctr = flags + 1024;
    unsigned int* mf   = flags + 1536;

    k_init<<<8, 256, 0, stream>>>(Wih2, Srow, flags);

    k_gemm_gi<<<dim3(24, 8), 256, 0, stream>>>(Wih1, bih1, emb, sentA, sentB, gi_buf);

    k_pipe<<<64, 512, 0, stream>>>(Whh1, bhh1, Wih1, bih1, gi_buf,
                                   e2x, hbuf0, hbuf1, fL0, fL1);

    k_tail<<<32, 512, 0, stream>>>(Wih1, bih1, Whh1, bhh1, convw, convb,
                                   Whh2, bhh2, bih2, Srow, e2x,
                                   WA, WB, b_bi, Wlin, blin,
                                   tb0, tb1, tr, Mmax, tctr, mf, (float*)d_out);
}